// Round 1
// baseline (92.882 us; speedup 1.0000x reference)
//
#include <hip/hip_runtime.h>
#include <cstdint>
#include <cstddef>

#define N_NODES 50000
#define M_MOLS  512
#define DIMK    256
#define ODIM    256

typedef float  f32x4  __attribute__((ext_vector_type(4)));
typedef __bf16 bf16x8 __attribute__((ext_vector_type(8)));

static __device__ __forceinline__ short f2bf(float f) {
  unsigned u = __builtin_bit_cast(unsigned, f);
  u = u + 0x7fffu + ((u >> 16) & 1u);   // RNE to bf16
  return (short)(u >> 16);
}

// a[n] = x[n,:] . w_align + b_align   (8 threads per row)
__global__ void k_align(const float* __restrict__ x, const float* __restrict__ w,
                        const float* __restrict__ b, float* __restrict__ a) {
  int tid = blockIdx.x * 256 + threadIdx.x;
  int row = tid >> 3, sub = tid & 7;
  if (row >= N_NODES) return;
  const float4* xr = (const float4*)(x + (size_t)row * DIMK) + sub * 8;
  const float4* wr = (const float4*)w + sub * 8;
  float s = 0.f;
#pragma unroll
  for (int i = 0; i < 8; i++) {
    float4 xv = xr[i], wv = wr[i];
    s += xv.x * wv.x + xv.y * wv.y + xv.z * wv.z + xv.w * wv.w;
  }
  s += __shfl_xor(s, 1); s += __shfl_xor(s, 2); s += __shfl_xor(s, 4);
  if (sub == 0) a[row] = s + b[0];
}

__global__ void k_zero_molid(int* __restrict__ molid) {
  int i = blockIdx.x * 256 + threadIdx.x;
  if (i < N_NODES / 4) *(int4*)(molid + i * 4) = make_int4(0, 0, 0, 0);
}

// mol_id[n] = row index of the single 1 in column n of mol_node_matrix
__global__ void k_molid(const float* __restrict__ mat, int* __restrict__ molid) {
  int n4 = blockIdx.x * 256 + threadIdx.x;
  if (n4 >= N_NODES / 4) return;
  int m0 = blockIdx.y * 32;
  int f0 = 0, f1 = 0, f2 = 0, f3 = 0;
  const float* base = mat + (size_t)m0 * N_NODES + (size_t)n4 * 4;
#pragma unroll
  for (int i = 0; i < 32; i++) {
    float4 v = *(const float4*)(base + (size_t)i * N_NODES);
    int m = m0 + i;
    if (v.x != 0.f) f0 = m;
    if (v.y != 0.f) f1 = m;
    if (v.z != 0.f) f2 = m;
    if (v.w != 0.f) f3 = m;
  }
  int n = n4 * 4;
  if (f0 > 0) molid[n]     = f0;
  if (f1 > 0) molid[n + 1] = f1;
  if (f2 > 0) molid[n + 2] = f2;
  if (f3 > 0) molid[n + 3] = f3;
}

// start[m] = first n with molid[n] >= m ; start[M] = N  (segments contiguous, ids sorted)
__global__ void k_bounds(const int* __restrict__ molid, int* __restrict__ start) {
  int n = blockIdx.x * 256 + threadIdx.x;
  if (n >= N_NODES) return;
  int cur  = molid[n];
  int prev = (n == 0) ? -1 : molid[n - 1];
  for (int m = prev + 1; m <= cur; m++) start[m] = n;
  if (n == N_NODES - 1) { for (int m = cur + 1; m <= M_MOLS; m++) start[m] = N_NODES; }
}

// per-molecule max and 1/sum(exp) — one block per molecule, deterministic tree reduce
__global__ void k_stats(const float* __restrict__ a, const int* __restrict__ start,
                        float* __restrict__ mmax, float* __restrict__ minv) {
  int m = blockIdx.x;
  int s = start[m], e = start[m + 1];
  int t = threadIdx.x;
  float mx = -3e38f;
  for (int i = s + t; i < e; i += 256) mx = fmaxf(mx, a[i]);
#pragma unroll
  for (int o = 1; o < 64; o <<= 1) mx = fmaxf(mx, __shfl_xor(mx, o));
  __shared__ float r0[4];
  if ((t & 63) == 0) r0[t >> 6] = mx;
  __syncthreads();
  mx = fmaxf(fmaxf(r0[0], r0[1]), fmaxf(r0[2], r0[3]));
  float sm = 0.f;
  for (int i = s + t; i < e; i += 256) sm += __expf(a[i] - mx);
#pragma unroll
  for (int o = 1; o < 64; o <<= 1) sm += __shfl_xor(sm, o);
  __shared__ float r1[4];
  if ((t & 63) == 0) r1[t >> 6] = sm;
  __syncthreads();
  sm = r1[0] + r1[1] + r1[2] + r1[3];
  if (t == 0) { mmax[m] = mx; minv[m] = (sm > 0.f) ? 1.f / sm : 0.f; }
}

// wval[n] = softmax weight of node n within its molecule
__global__ void k_wval(const float* __restrict__ a, const int* __restrict__ molid,
                       const float* __restrict__ mmax, const float* __restrict__ minv,
                       float* __restrict__ wval) {
  int n = blockIdx.x * 256 + threadIdx.x;
  if (n >= N_NODES) return;
  int m = molid[n];
  wval[n] = __expf(a[n] - mmax[m]) * minv[m];
}

// out1[m][n] = (molid[n]==m) ? wval[n] : 0   — single streaming write pass
__global__ void k_weights(const int* __restrict__ molid, const float* __restrict__ wval,
                          float* __restrict__ out1) {
  int n4 = blockIdx.x * 256 + threadIdx.x;
  if (n4 >= N_NODES / 4) return;
  int m = blockIdx.y;
  int4   id = *(const int4*)(molid + n4 * 4);
  float4 w  = *(const float4*)(wval + n4 * 4);
  float4 o;
  o.x = (id.x == m) ? w.x : 0.f;
  o.y = (id.y == m) ? w.y : 0.f;
  o.z = (id.z == m) ? w.z : 0.f;
  o.w = (id.w == m) ? w.w : 0.f;
  *(float4*)(out1 + (size_t)m * N_NODES + (size_t)n4 * 4) = o;
}

// Pack W_attend into MFMA B-fragment layout (bf16), coalesced for k_pool:
// wp[(J*8+u)*64 + l] = { W[k][j] : j = J*16+(l&15), k = u*32+(l>>4)*8 .. +8 }
__global__ void k_wpack(const float* __restrict__ W, int4* __restrict__ wp) {
  int l = threadIdx.x;   // 64
  int J = blockIdx.x;    // 16
  int u = blockIdx.y;    // 8
  int j  = J * 16 + (l & 15);
  int k0 = u * 32 + (l >> 4) * 8;
  short sv[8];
#pragma unroll
  for (int i = 0; i < 8; i++) sv[i] = f2bf(W[(size_t)(k0 + i) * ODIM + j]);
  wp[(J * 8 + u) * 64 + l] = *(int4*)sv;
}

// Fused h-GEMM + pooling: one block (4 waves) per molecule.
// out0[m][j] = sum_n wval[n] * LeakyReLU( (x[n]@W)[j] + bias[j] )
__global__ __launch_bounds__(256, 2) void k_pool(
    const float* __restrict__ x, const float* __restrict__ a,
    const int* __restrict__ start, const float* __restrict__ mmax,
    const float* __restrict__ minv, const int4* __restrict__ wp,
    const float* __restrict__ bias, float* __restrict__ out0) {
  int m = blockIdx.x;
  int s = start[m], e = start[m + 1];
  int tid  = threadIdx.x;
  int wave = tid >> 6, l = tid & 63;

  // hoist this wave's W fragments (4 j-subtiles x 8 k-steps) into VGPRs
  bf16x8 wfrag[4][8];
#pragma unroll
  for (int t = 0; t < 4; t++)
#pragma unroll
    for (int u = 0; u < 8; u++) {
      int J = wave * 4 + t;
      int4 raw = wp[(J * 8 + u) * 64 + l];
      wfrag[t][u] = __builtin_bit_cast(bf16x8, raw);
    }
  float bias_r[4];
#pragma unroll
  for (int t = 0; t < 4; t++) bias_r[t] = bias[wave * 64 + t * 16 + (l & 15)];

  float mx = mmax[m], inv = minv[m];
  float pooled[4] = {0.f, 0.f, 0.f, 0.f};

  __shared__ __align__(16) short xs[16 * 256];  // 16-node x-tile, bf16, XOR-swizzled
  __shared__ float wt[16];

  int r = l & 15, g = l >> 4;
  int swr = (r & 7) << 4;

  int nt = (e - s + 15) >> 4;
  for (int tile = 0; tile < nt; ++tile) {
    int base = s + tile * 16;
    __syncthreads();  // protect xs/wt of previous tile
    {   // stage 16 rows of x -> bf16 LDS (coalesced global, swizzled LDS)
      int row = tid >> 4;
      int c0  = (tid & 15) * 16;
      int n   = base + row;
      float v[16];
      if (n < e) {
        const float4* src = (const float4*)(x + (size_t)n * DIMK + c0);
        float4 A = src[0], B = src[1], C = src[2], D = src[3];
        v[0]=A.x; v[1]=A.y; v[2]=A.z; v[3]=A.w;
        v[4]=B.x; v[5]=B.y; v[6]=B.z; v[7]=B.w;
        v[8]=C.x; v[9]=C.y; v[10]=C.z; v[11]=C.w;
        v[12]=D.x; v[13]=D.y; v[14]=D.z; v[15]=D.w;
      } else {
#pragma unroll
        for (int i = 0; i < 16; i++) v[i] = 0.f;
      }
      short sv[16];
#pragma unroll
      for (int i = 0; i < 16; i++) sv[i] = f2bf(v[i]);
      int sw = (row & 7) << 4;
      char* lb = (char*)xs;
      *(int4*)(lb + (row << 9) + (((c0 << 1)     ) ^ sw)) = *(int4*)(sv);
      *(int4*)(lb + (row << 9) + (((c0 << 1) + 16) ^ sw)) = *(int4*)(sv + 8);
      if (tid < 16) {
        int nn = base + tid;
        wt[tid] = (nn < e) ? __expf(a[nn] - mx) * inv : 0.f;
      }
    }
    __syncthreads();
    // A-fragments from LDS (swizzled b128 reads)
    bf16x8 af[8];
    const char* lb = (const char*)xs;
#pragma unroll
    for (int u = 0; u < 8; u++) {
      int addr = (r << 9) + ((((u << 6) + (g << 4))) ^ swr);
      int4 raw = *(const int4*)(lb + addr);
      af[u] = __builtin_bit_cast(bf16x8, raw);
    }
#pragma unroll
    for (int t = 0; t < 4; t++) {
      f32x4 acc = {0.f, 0.f, 0.f, 0.f};
#pragma unroll
      for (int u = 0; u < 8; u++)
        acc = __builtin_amdgcn_mfma_f32_16x16x32_bf16(af[u], wfrag[t][u], acc, 0, 0, 0);
      // D layout: col j = l&15 (+16t+64w), rows = g*4+i ; weight rows, relu, pool
      float p = 0.f;
#pragma unroll
      for (int i = 0; i < 4; i++) {
        float h = acc[i] + bias_r[t];
        h = h > 0.f ? h : 0.01f * h;
        p += wt[(g << 2) + i] * h;
      }
      pooled[t] += p;
    }
  }
  // reduce partial row-sums across the 4 lane-groups
#pragma unroll
  for (int t = 0; t < 4; t++) {
    float p = pooled[t];
    p += __shfl_xor(p, 16);
    p += __shfl_xor(p, 32);
    pooled[t] = p;
  }
  if (l < 16) {
#pragma unroll
    for (int t = 0; t < 4; t++)
      out0[m * ODIM + wave * 64 + t * 16 + l] = pooled[t];
  }
}

extern "C" void kernel_launch(void* const* d_in, const int* in_sizes, int n_in,
                              void* d_out, int out_size, void* d_ws, size_t ws_size,
                              hipStream_t stream) {
  const float* x   = (const float*)d_in[0];
  const float* mat = (const float*)d_in[1];
  // d_in[2] (mol_node_mask) is redundant with mol_node_matrix — never read
  const float* W   = (const float*)d_in[3];
  const float* bA  = (const float*)d_in[4];
  const float* wa  = (const float*)d_in[5];
  const float* ba  = (const float*)d_in[6];

  float* out0 = (float*)d_out;
  float* out1 = out0 + (size_t)M_MOLS * ODIM;

  char*  ws    = (char*)d_ws;
  float* a     = (float*)(ws);             // 50000 f
  int*   molid = (int*)  (ws + 200000);    // 50000 i
  int*   strt  = (int*)  (ws + 400000);    // 513 i
  float* mmx   = (float*)(ws + 404096);    // 512 f
  float* minv  = (float*)(ws + 406144);    // 512 f
  float* wval  = (float*)(ws + 408192);    // 50000 f
  int4*  wp    = (int4*) (ws + 608192);    // 128 KiB

  k_wpack <<<dim3(16, 8), 64, 0, stream>>>(W, wp);
  k_align <<<(N_NODES * 8 + 255) / 256, 256, 0, stream>>>(x, wa, ba, a);
  k_zero_molid<<<49, 256, 0, stream>>>(molid);
  k_molid <<<dim3(49, 16), 256, 0, stream>>>(mat, molid);
  k_bounds<<<196, 256, 0, stream>>>(molid, strt);
  k_stats <<<512, 256, 0, stream>>>(a, strt, mmx, minv);
  k_wval  <<<196, 256, 0, stream>>>(a, molid, mmx, minv, wval);
  k_weights<<<dim3(49, 512), 256, 0, stream>>>(molid, wval, out1);
  k_pool  <<<512, 256, 0, stream>>>(x, a, strt, mmx, minv, wp, bA, out0);
}

// Round 2
// 67.481 us; speedup vs baseline: 1.3764x; 1.3764x over previous
//
#include <hip/hip_runtime.h>
#include <cstdint>
#include <cstddef>

#define N_NODES 50000
#define M_MOLS  512
#define DIMK    256
#define ODIM    256

#define NB_MOLID 196      // 256 columns each
#define NB_ALIGN 1563     // 32 rows each (8 threads/row)
#define NB_WPACK 32       // 8192 work items
#define P1_GRID  (NB_MOLID + NB_ALIGN + NB_WPACK)

#define POOL_BLOCKS 512
#define WCHUNK 49         // column chunks of 1024
#define WROWS  8          // m-rows per weights block
#define NB_WEIGHT (WCHUNK * (M_MOLS / WROWS))   // 3136
#define C_GRID (POOL_BLOCKS + NB_WEIGHT)        // 3648

typedef float  f32x4  __attribute__((ext_vector_type(4)));
typedef __bf16 bf16x8 __attribute__((ext_vector_type(8)));

static __device__ __forceinline__ short f2bf(float f) {
  unsigned u = __builtin_bit_cast(unsigned, f);
  u = u + 0x7fffu + ((u >> 16) & 1u);   // RNE to bf16
  return (short)(u >> 16);
}

// ---------------- phase 1: molid scan + align GEMV + W pack ----------------
__global__ __launch_bounds__(256) void k_phase1(
    const float* __restrict__ x, const float* __restrict__ mat,
    const float* __restrict__ W, const float* __restrict__ wa,
    const float* __restrict__ ba,
    float* __restrict__ a, int* __restrict__ molid, int4* __restrict__ wp) {
  int b = blockIdx.x;
  int t = threadIdx.x;
  if (b < NB_MOLID) {
    // molid: each thread owns one column, scans all 512 rows (race-free)
    int n = b * 256 + t;
    if (n >= N_NODES) return;
    const float* p = mat + n;
    int id = 0;
#pragma unroll 16
    for (int m = 0; m < M_MOLS; m++) {
      float v = p[(size_t)m * N_NODES];
      if (v != 0.f) id = m;
    }
    molid[n] = id;
  } else if (b < NB_MOLID + NB_ALIGN) {
    // align: a[n] = x[n,:].w_align + b_align, 8 threads per row
    int tid = (b - NB_MOLID) * 256 + t;
    int row = tid >> 3, sub = tid & 7;
    if (row >= N_NODES) return;
    const float4* xr = (const float4*)(x + (size_t)row * DIMK) + sub * 8;
    const float4* wr = (const float4*)wa + sub * 8;
    float s = 0.f;
#pragma unroll
    for (int i = 0; i < 8; i++) {
      float4 xv = xr[i], wv = wr[i];
      s += xv.x * wv.x + xv.y * wv.y + xv.z * wv.z + xv.w * wv.w;
    }
    s += __shfl_xor(s, 1); s += __shfl_xor(s, 2); s += __shfl_xor(s, 4);
    if (sub == 0) a[row] = s + ba[0];
  } else {
    // W pack into MFMA B-fragment layout (bf16)
    int g  = (b - NB_MOLID - NB_ALIGN) * 256 + t;  // 0..8191
    int l  = g & 63;
    int Ju = g >> 6;            // 0..127 : J = Ju>>3, u = Ju&7
    int J  = Ju >> 3, u = Ju & 7;
    int j  = J * 16 + (l & 15);
    int k0 = u * 32 + (l >> 4) * 8;
    short sv[8];
#pragma unroll
    for (int i = 0; i < 8; i++) sv[i] = f2bf(W[(size_t)(k0 + i) * ODIM + j]);
    wp[Ju * 64 + l] = *(int4*)sv;
  }
}

// ---------------- phase 2: bounds (binary search) + softmax stats + wval ----
__global__ __launch_bounds__(256) void k_phase2(
    const float* __restrict__ a, const int* __restrict__ molid,
    int* __restrict__ strt, float* __restrict__ wval) {
  int m = blockIdx.x;
  int t = threadIdx.x;
  __shared__ int sse[2];
  if (t < 2) {
    int target = m + t;
    int lo = 0, hi = N_NODES;
    while (lo < hi) { int mid = (lo + hi) >> 1; if (molid[mid] < target) lo = mid + 1; else hi = mid; }
    sse[t] = lo;
    if (t == 0) strt[m] = lo;
    if (m == M_MOLS - 1 && t == 1) strt[M_MOLS] = lo;   // = N_NODES
  }
  __syncthreads();
  int s = sse[0], e = sse[1];

  float mx = -3e38f;
  for (int i = s + t; i < e; i += 256) mx = fmaxf(mx, a[i]);
#pragma unroll
  for (int o = 1; o < 64; o <<= 1) mx = fmaxf(mx, __shfl_xor(mx, o));
  __shared__ float r0[4];
  if ((t & 63) == 0) r0[t >> 6] = mx;
  __syncthreads();
  mx = fmaxf(fmaxf(r0[0], r0[1]), fmaxf(r0[2], r0[3]));

  float sm = 0.f;
  for (int i = s + t; i < e; i += 256) sm += __expf(a[i] - mx);
#pragma unroll
  for (int o = 1; o < 64; o <<= 1) sm += __shfl_xor(sm, o);
  __shared__ float r1[4];
  if ((t & 63) == 0) r1[t >> 6] = sm;
  __syncthreads();
  sm = r1[0] + r1[1] + r1[2] + r1[3];
  float inv = (sm > 0.f) ? 1.f / sm : 0.f;

  for (int i = s + t; i < e; i += 256) wval[i] = __expf(a[i] - mx) * inv;
}

// ---------------- phase 3: weights writer + fused pool (interleaved) --------
__global__ __launch_bounds__(256, 2) void k_phase3(
    const float* __restrict__ x, const float* __restrict__ wval,
    const int* __restrict__ strt, const int4* __restrict__ wp,
    const float* __restrict__ bias, float* __restrict__ out0,
    float* __restrict__ out1) {
  int b  = blockIdx.x;
  int pb = b / 7;
  bool isPool = ((b % 7) == 0) && (pb < POOL_BLOCKS);

  if (!isPool) {
    // ---- streaming weights writer: out1[m][n] = in-segment ? wval[n] : 0
    int before = (pb < POOL_BLOCKS) ? (pb + 1) : POOL_BLOCKS;
    int wb = b - before;                 // 0..3135
    int mc = wb / WCHUNK;                // 0..63
    int c  = wb % WCHUNK;                // 0..48
    int t  = threadIdx.x;
    int n4 = c * 256 + t;
    if (n4 >= N_NODES / 4) return;
    int n = n4 * 4;
    float4 w = *(const float4*)(wval + n);
    int m0 = mc * WROWS;
#pragma unroll
    for (int r = 0; r < WROWS; r++) {
      int m = m0 + r;
      int s = strt[m], e = strt[m + 1];
      float4 o;
      o.x = ((unsigned)(n     - s) < (unsigned)(e - s)) ? w.x : 0.f;
      o.y = ((unsigned)(n + 1 - s) < (unsigned)(e - s)) ? w.y : 0.f;
      o.z = ((unsigned)(n + 2 - s) < (unsigned)(e - s)) ? w.z : 0.f;
      o.w = ((unsigned)(n + 3 - s) < (unsigned)(e - s)) ? w.w : 0.f;
      *(float4*)(out1 + (size_t)m * N_NODES + n) = o;
    }
    return;
  }

  // ---- fused h-GEMM + pooling for molecule m = pb
  int m = pb;
  int s = strt[m], e = strt[m + 1];
  int tid  = threadIdx.x;
  int wave = tid >> 6, l = tid & 63;

  bf16x8 wfrag[4][8];
#pragma unroll
  for (int t2 = 0; t2 < 4; t2++)
#pragma unroll
    for (int u = 0; u < 8; u++) {
      int Ju = (wave * 4 + t2) * 8 + u;
      wfrag[t2][u] = __builtin_bit_cast(bf16x8, wp[Ju * 64 + l]);
    }
  float bias_r[4];
#pragma unroll
  for (int t2 = 0; t2 < 4; t2++) bias_r[t2] = bias[wave * 64 + t2 * 16 + (l & 15)];

  float pooled[4] = {0.f, 0.f, 0.f, 0.f};

  __shared__ __align__(16) short xs[16 * 256];
  __shared__ float wt[16];

  int r = l & 15, g = l >> 4;
  int swr = (r & 7) << 4;

  int nt = (e - s + 15) >> 4;
  for (int tile = 0; tile < nt; ++tile) {
    int base = s + tile * 16;
    __syncthreads();
    {
      int row = tid >> 4;
      int c0  = (tid & 15) * 16;
      int n   = base + row;
      float v[16];
      if (n < e) {
        const float4* src = (const float4*)(x + (size_t)n * DIMK + c0);
        float4 A = src[0], B = src[1], C = src[2], D = src[3];
        v[0]=A.x; v[1]=A.y; v[2]=A.z; v[3]=A.w;
        v[4]=B.x; v[5]=B.y; v[6]=B.z; v[7]=B.w;
        v[8]=C.x; v[9]=C.y; v[10]=C.z; v[11]=C.w;
        v[12]=D.x; v[13]=D.y; v[14]=D.z; v[15]=D.w;
      } else {
#pragma unroll
        for (int i = 0; i < 16; i++) v[i] = 0.f;
      }
      short sv[16];
#pragma unroll
      for (int i = 0; i < 16; i++) sv[i] = f2bf(v[i]);
      int sw = (row & 7) << 4;
      char* lb = (char*)xs;
      *(int4*)(lb + (row << 9) + (((c0 << 1)     ) ^ sw)) = *(int4*)(sv);
      *(int4*)(lb + (row << 9) + (((c0 << 1) + 16) ^ sw)) = *(int4*)(sv + 8);
      if (tid < 16) {
        int nn = base + tid;
        wt[tid] = (nn < e) ? wval[nn] : 0.f;
      }
    }
    __syncthreads();
    bf16x8 af[8];
    const char* lb = (const char*)xs;
#pragma unroll
    for (int u = 0; u < 8; u++) {
      int addr = (r << 9) + ((((u << 6) + (g << 4))) ^ swr);
      af[u] = __builtin_bit_cast(bf16x8, *(const int4*)(lb + addr));
    }
#pragma unroll
    for (int t2 = 0; t2 < 4; t2++) {
      f32x4 acc = {0.f, 0.f, 0.f, 0.f};
#pragma unroll
      for (int u = 0; u < 8; u++)
        acc = __builtin_amdgcn_mfma_f32_16x16x32_bf16(af[u], wfrag[t2][u], acc, 0, 0, 0);
      float p = 0.f;
#pragma unroll
      for (int i = 0; i < 4; i++) {
        float h = acc[i] + bias_r[t2];
        h = h > 0.f ? h : 0.01f * h;
        p += wt[(g << 2) + i] * h;
      }
      pooled[t2] += p;
    }
  }
#pragma unroll
  for (int t2 = 0; t2 < 4; t2++) {
    float p = pooled[t2];
    p += __shfl_xor(p, 16);
    p += __shfl_xor(p, 32);
    pooled[t2] = p;
  }
  if (l < 16) {
#pragma unroll
    for (int t2 = 0; t2 < 4; t2++)
      out0[m * ODIM + wave * 64 + t2 * 16 + l] = pooled[t2];
  }
}

extern "C" void kernel_launch(void* const* d_in, const int* in_sizes, int n_in,
                              void* d_out, int out_size, void* d_ws, size_t ws_size,
                              hipStream_t stream) {
  const float* x   = (const float*)d_in[0];
  const float* mat = (const float*)d_in[1];
  // d_in[2] (mol_node_mask) redundant with mol_node_matrix — never read
  const float* W   = (const float*)d_in[3];
  const float* bA  = (const float*)d_in[4];
  const float* wa  = (const float*)d_in[5];
  const float* ba  = (const float*)d_in[6];

  float* out0 = (float*)d_out;
  float* out1 = out0 + (size_t)M_MOLS * ODIM;

  char*  ws    = (char*)d_ws;
  float* a     = (float*)(ws);             // 50000 f
  int*   molid = (int*)  (ws + 200000);    // 50000 i
  int*   strt  = (int*)  (ws + 400000);    // 513 i
  float* wval  = (float*)(ws + 402064);    // 50000 f
  int4*  wp    = (int4*) (ws + 602112);    // 128 KiB

  k_phase1<<<P1_GRID, 256, 0, stream>>>(x, mat, W, wa, ba, a, molid, wp);
  k_phase2<<<M_MOLS, 256, 0, stream>>>(a, molid, strt, wval);
  k_phase3<<<C_GRID, 256, 0, stream>>>(x, wval, strt, wp, bA, out0, out1);
}

// Round 3
// 59.281 us; speedup vs baseline: 1.5668x; 1.1383x over previous
//
#include <hip/hip_runtime.h>
#include <cstdint>
#include <cstddef>

#define N_NODES 50000
#define M_MOLS  512
#define DIMK    256
#define ODIM    256

// ---- sampled-boundary parameters ----
#define NCH   99          // sample chunks
#define CW    32          // columns per chunk
#define NSAMP (NCH * CW)  // 3168 sampled columns (monotone molid sequence)
#define NGAP  (NCH - 1)   // 98 inter-chunk gaps

#define NB_SAMP  NCH
#define NB_ALIGN 1563     // 50000 rows * 8 threads / 256
#define NB_WPACK 32       // 8192 work items
#define P1_GRID  (NB_SAMP + NB_ALIGN + NB_WPACK)

#define POOL_BLOCKS 512
#define WCHUNK 49         // column chunks of 1024
#define WROWS  8          // m-rows per weights block
#define NB_WEIGHT (WCHUNK * (M_MOLS / WROWS))   // 3136
#define C_GRID (POOL_BLOCKS + NB_WEIGHT)        // 3648

typedef float  f32x4  __attribute__((ext_vector_type(4)));
typedef __bf16 bf16x8 __attribute__((ext_vector_type(8)));

static __device__ __forceinline__ short f2bf(float f) {
  unsigned u = __builtin_bit_cast(unsigned, f);
  u = u + 0x7fffu + ((u >> 16) & 1u);   // RNE to bf16
  return (short)(u >> 16);
}

// chunk c covers columns [chunk_base(c), chunk_base(c)+32); bases 128B-aligned,
// last chunk pinned so column N-1 is sampled.
static __device__ __forceinline__ int chunk_base(int c) {
  return (c < NCH - 1) ? c * 512 : (N_NODES - CW);   // 49968
}

// ---------------- K1: sampled molid + align GEMV + W pack ----------------
__global__ __launch_bounds__(256) void k_phase1(
    const float* __restrict__ x, const float* __restrict__ mat,
    const float* __restrict__ W, const float* __restrict__ wa,
    const float* __restrict__ ba,
    float* __restrict__ a, int* __restrict__ smolid, int4* __restrict__ wp) {
  int b = blockIdx.x, t = threadIdx.x;
  if (b < NB_SAMP) {
    // molid at 32 sampled columns: one-hot per column -> max row with nonzero
    int base = chunk_base(b);
    int cp = (t & 15) * 2;      // column pair
    int rg = t >> 4;            // 16 row-groups of 32 rows
    int idx = -1, idy = -1;
    const float* p0 = mat + (size_t)(rg * 32) * N_NODES + base + cp;
#pragma unroll 16
    for (int r = 0; r < 32; r++) {
      float2 v = *(const float2*)(p0 + (size_t)r * N_NODES);
      if (v.x != 0.f) idx = rg * 32 + r;
      if (v.y != 0.f) idy = rg * 32 + r;
    }
    __shared__ int sm[16][32];
    sm[rg][cp] = idx; sm[rg][cp + 1] = idy;
    __syncthreads();
    if (t < 32) {
      int best = -1;
#pragma unroll
      for (int g = 0; g < 16; g++) best = max(best, sm[g][t]);
      smolid[b * CW + t] = best;
    }
  } else if (b < NB_SAMP + NB_ALIGN) {
    // align: a[n] = x[n,:].w_align + b_align, 8 threads per row
    int tid = (b - NB_SAMP) * 256 + t;
    int row = tid >> 3, sub = tid & 7;
    if (row >= N_NODES) return;
    const float4* xr = (const float4*)(x + (size_t)row * DIMK) + sub * 8;
    const float4* wr = (const float4*)wa + sub * 8;
    float s = 0.f;
#pragma unroll
    for (int i = 0; i < 8; i++) {
      float4 xv = xr[i], wv = wr[i];
      s += xv.x * wv.x + xv.y * wv.y + xv.z * wv.z + xv.w * wv.w;
    }
    s += __shfl_xor(s, 1); s += __shfl_xor(s, 2); s += __shfl_xor(s, 4);
    if (sub == 0) a[row] = s + ba[0];
  } else {
    // W pack into MFMA B-fragment layout (bf16)
    int g  = (b - NB_SAMP - NB_ALIGN) * 256 + t;  // 0..8191
    int l  = g & 63;
    int Ju = g >> 6;
    int J  = Ju >> 3, u = Ju & 7;
    int j  = J * 16 + (l & 15);
    int k0 = u * 32 + (l >> 4) * 8;
    short sv[8];
#pragma unroll
    for (int i = 0; i < 8; i++) sv[i] = f2bf(W[(size_t)(k0 + i) * ODIM + j]);
    wp[Ju * 64 + l] = *(int4*)sv;
  }
}

// ---------------- K2: exact boundary resolution from samples ----------------
// strt[m] = first column n with molid(n) >= m.
__global__ __launch_bounds__(256) void k_bounds(
    const float* __restrict__ mat, const int* __restrict__ smolid,
    int* __restrict__ strt) {
  int b = blockIdx.x, t = threadIdx.x;
  if (b < NGAP) {
    // gap between chunk b (last col p) and chunk b+1 (first col q)
    int p  = chunk_base(b) + CW - 1;
    int q  = chunk_base(b + 1);
    int ag = smolid[b * CW + CW - 1];   // molid(p)
    int bg = smolid[(b + 1) * CW];      // molid(q)
    if (bg == ag) return;
    int Wd = q - p;                     // columns p+1 .. q
    int nr = bg - ag;                   // rows ag+1 .. bg
    __shared__ int f1[512];
    int wave = t >> 6, l = t & 63;
    for (int rr = wave; rr < nr; rr += 4) {
      const float* rp = mat + (size_t)(ag + 1 + rr) * N_NODES + p + 1;
      int mn = 0x7fffffff;
      for (int i = l; i < Wd; i += 64)
        if (rp[i] != 0.f) { mn = i; break; }   // ascending -> first hit is min
#pragma unroll
      for (int o = 1; o < 64; o <<= 1) mn = min(mn, __shfl_xor(mn, o));
      if (l == 0) f1[rr] = mn;
    }
    __syncthreads();
    if (t == 0) {
      // suffix-min resolves empty segments; row bg always has a 1 at col q
      int run = 0x7fffffff;
      for (int rr = nr - 1; rr >= 0; rr--) {
        run = min(run, f1[rr]);
        strt[ag + 1 + rr] = p + 1 + run;
      }
    }
  } else if (b < NGAP + NCH) {
    // in-chunk transitions between adjacent sampled columns
    int cc = b - NGAP;
    if (t >= 1 && t < CW) {
      int prev = smolid[cc * CW + t - 1], cur = smolid[cc * CW + t];
      int col = chunk_base(cc) + t;
      for (int m = prev + 1; m <= cur; m++) strt[m] = col;
    }
  } else {
    // cleanup: head (m <= molid(0)) -> 0 ; tail (m > molid(N-1)) -> N
    int first = smolid[0], last = smolid[NSAMP - 1];
    for (int m = t; m <= M_MOLS; m += 256) {
      if (m <= first) strt[m] = 0;
      else if (m > last) strt[m] = N_NODES;
    }
  }
}

// ---------------- K3: softmax stats + wval ----------------
__global__ __launch_bounds__(256) void k_stats(
    const float* __restrict__ a, const int* __restrict__ strt,
    float* __restrict__ wval) {
  int m = blockIdx.x, t = threadIdx.x;
  int s = strt[m], e = strt[m + 1];

  float mx = -3e38f;
  for (int i = s + t; i < e; i += 256) mx = fmaxf(mx, a[i]);
#pragma unroll
  for (int o = 1; o < 64; o <<= 1) mx = fmaxf(mx, __shfl_xor(mx, o));
  __shared__ float r0[4];
  if ((t & 63) == 0) r0[t >> 6] = mx;
  __syncthreads();
  mx = fmaxf(fmaxf(r0[0], r0[1]), fmaxf(r0[2], r0[3]));

  float sm = 0.f;
  for (int i = s + t; i < e; i += 256) sm += __expf(a[i] - mx);
#pragma unroll
  for (int o = 1; o < 64; o <<= 1) sm += __shfl_xor(sm, o);
  __shared__ float r1[4];
  if ((t & 63) == 0) r1[t >> 6] = sm;
  __syncthreads();
  sm = r1[0] + r1[1] + r1[2] + r1[3];
  float inv = (sm > 0.f) ? 1.f / sm : 0.f;

  for (int i = s + t; i < e; i += 256) wval[i] = __expf(a[i] - mx) * inv;
}

// ---------------- K4: weights writer + fused pool (interleaved) --------
__global__ __launch_bounds__(256, 2) void k_phase3(
    const float* __restrict__ x, const float* __restrict__ wval,
    const int* __restrict__ strt, const int4* __restrict__ wp,
    const float* __restrict__ bias, float* __restrict__ out0,
    float* __restrict__ out1) {
  int b  = blockIdx.x;
  int pb = b / 7;
  bool isPool = ((b % 7) == 0) && (pb < POOL_BLOCKS);

  if (!isPool) {
    int before = (pb < POOL_BLOCKS) ? (pb + 1) : POOL_BLOCKS;
    int wb = b - before;                 // 0..3135
    int mc = wb / WCHUNK;                // 0..63
    int c  = wb % WCHUNK;                // 0..48
    int t  = threadIdx.x;
    int n4 = c * 256 + t;
    if (n4 >= N_NODES / 4) return;
    int n = n4 * 4;
    float4 w = *(const float4*)(wval + n);
    int m0 = mc * WROWS;
#pragma unroll
    for (int r = 0; r < WROWS; r++) {
      int m = m0 + r;
      int s = strt[m], e = strt[m + 1];
      float4 o;
      o.x = ((unsigned)(n     - s) < (unsigned)(e - s)) ? w.x : 0.f;
      o.y = ((unsigned)(n + 1 - s) < (unsigned)(e - s)) ? w.y : 0.f;
      o.z = ((unsigned)(n + 2 - s) < (unsigned)(e - s)) ? w.z : 0.f;
      o.w = ((unsigned)(n + 3 - s) < (unsigned)(e - s)) ? w.w : 0.f;
      *(float4*)(out1 + (size_t)m * N_NODES + n) = o;
    }
    return;
  }

  // fused h-GEMM + pooling for molecule m = pb
  int m = pb;
  int s = strt[m], e = strt[m + 1];
  int tid  = threadIdx.x;
  int wave = tid >> 6, l = tid & 63;

  bf16x8 wfrag[4][8];
#pragma unroll
  for (int t2 = 0; t2 < 4; t2++)
#pragma unroll
    for (int u = 0; u < 8; u++) {
      int Ju = (wave * 4 + t2) * 8 + u;
      wfrag[t2][u] = __builtin_bit_cast(bf16x8, wp[Ju * 64 + l]);
    }
  float bias_r[4];
#pragma unroll
  for (int t2 = 0; t2 < 4; t2++) bias_r[t2] = bias[wave * 64 + t2 * 16 + (l & 15)];

  float pooled[4] = {0.f, 0.f, 0.f, 0.f};

  __shared__ __align__(16) short xs[16 * 256];
  __shared__ float wt[16];

  int r = l & 15, g = l >> 4;
  int swr = (r & 7) << 4;

  int nt = (e - s + 15) >> 4;
  for (int tile = 0; tile < nt; ++tile) {
    int base = s + tile * 16;
    __syncthreads();
    {
      int row = tid >> 4;
      int c0  = (tid & 15) * 16;
      int n   = base + row;
      float v[16];
      if (n < e) {
        const float4* src = (const float4*)(x + (size_t)n * DIMK + c0);
        float4 A = src[0], B = src[1], C = src[2], D = src[3];
        v[0]=A.x; v[1]=A.y; v[2]=A.z; v[3]=A.w;
        v[4]=B.x; v[5]=B.y; v[6]=B.z; v[7]=B.w;
        v[8]=C.x; v[9]=C.y; v[10]=C.z; v[11]=C.w;
        v[12]=D.x; v[13]=D.y; v[14]=D.z; v[15]=D.w;
      } else {
#pragma unroll
        for (int i = 0; i < 16; i++) v[i] = 0.f;
      }
      short sv[16];
#pragma unroll
      for (int i = 0; i < 16; i++) sv[i] = f2bf(v[i]);
      int sw = (row & 7) << 4;
      char* lb = (char*)xs;
      *(int4*)(lb + (row << 9) + (((c0 << 1)     ) ^ sw)) = *(int4*)(sv);
      *(int4*)(lb + (row << 9) + (((c0 << 1) + 16) ^ sw)) = *(int4*)(sv + 8);
      if (tid < 16) {
        int nn = base + tid;
        wt[tid] = (nn < e) ? wval[nn] : 0.f;
      }
    }
    __syncthreads();
    bf16x8 af[8];
    const char* lb = (const char*)xs;
#pragma unroll
    for (int u = 0; u < 8; u++) {
      int addr = (r << 9) + ((((u << 6) + (g << 4))) ^ swr);
      af[u] = __builtin_bit_cast(bf16x8, *(const int4*)(lb + addr));
    }
#pragma unroll
    for (int t2 = 0; t2 < 4; t2++) {
      f32x4 acc = {0.f, 0.f, 0.f, 0.f};
#pragma unroll
      for (int u = 0; u < 8; u++)
        acc = __builtin_amdgcn_mfma_f32_16x16x32_bf16(af[u], wfrag[t2][u], acc, 0, 0, 0);
      float p = 0.f;
#pragma unroll
      for (int i = 0; i < 4; i++) {
        float h = acc[i] + bias_r[t2];
        h = h > 0.f ? h : 0.01f * h;
        p += wt[(g << 2) + i] * h;
      }
      pooled[t2] += p;
    }
  }
#pragma unroll
  for (int t2 = 0; t2 < 4; t2++) {
    float p = pooled[t2];
    p += __shfl_xor(p, 16);
    p += __shfl_xor(p, 32);
    pooled[t2] = p;
  }
  if (l < 16) {
#pragma unroll
    for (int t2 = 0; t2 < 4; t2++)
      out0[m * ODIM + wave * 64 + t2 * 16 + l] = pooled[t2];
  }
}

extern "C" void kernel_launch(void* const* d_in, const int* in_sizes, int n_in,
                              void* d_out, int out_size, void* d_ws, size_t ws_size,
                              hipStream_t stream) {
  const float* x   = (const float*)d_in[0];
  const float* mat = (const float*)d_in[1];
  // d_in[2] (mol_node_mask) redundant with mol_node_matrix — never read
  const float* W   = (const float*)d_in[3];
  const float* bA  = (const float*)d_in[4];
  const float* wa  = (const float*)d_in[5];
  const float* ba  = (const float*)d_in[6];

  float* out0 = (float*)d_out;
  float* out1 = out0 + (size_t)M_MOLS * ODIM;

  char*  ws     = (char*)d_ws;
  float* a      = (float*)(ws);              // 50000 f
  int*   smolid = (int*)  (ws + 200064);     // 3168 i
  int*   strt   = (int*)  (ws + 212800);     // 513 i
  float* wval   = (float*)(ws + 214912);     // 50000 f
  int4*  wp     = (int4*) (ws + 414912);     // 128 KiB

  k_phase1<<<P1_GRID, 256, 0, stream>>>(x, mat, W, wa, ba, a, smolid, wp);
  k_bounds<<<NGAP + NCH + 1, 256, 0, stream>>>(mat, smolid, strt);
  k_stats <<<M_MOLS, 256, 0, stream>>>(a, strt, wval);
  k_phase3<<<C_GRID, 256, 0, stream>>>(x, wval, strt, wp, bA, out0, out1);
}

// Round 4
// 48.345 us; speedup vs baseline: 1.9212x; 1.2262x over previous
//
#include <hip/hip_runtime.h>
#include <cstdint>
#include <cstddef>

#define N_NODES 50000
#define M_MOLS  512
#define DIMK    256
#define ODIM    256

// sampled-boundary parameters
#define NCH   99
#define CW    32
#define NSAMP (NCH * CW)      // 3168 sampled columns, monotone molid

#define NB_SAMP  NCH
#define NB_WPACK 32
#define K1_GRID  (NB_SAMP + NB_WPACK)

#define K2T   512             // threads per k_main block
#define A_CAP 4096            // max segment length staged in LDS (mean ~98)
#define NF4   (N_NODES / 4)   // 12500 float4 per out1 row

typedef float  f32x4  __attribute__((ext_vector_type(4)));
typedef __bf16 bf16x8 __attribute__((ext_vector_type(8)));

static __device__ __forceinline__ short f2bf(float f) {
  unsigned u = __builtin_bit_cast(unsigned, f);
  u = u + 0x7fffu + ((u >> 16) & 1u);   // RNE to bf16
  return (short)(u >> 16);
}

// chunk c covers columns [chunk_base(c), chunk_base(c)+32)
static __device__ __forceinline__ int chunk_base(int c) {
  return (c < NCH - 1) ? c * 512 : (N_NODES - CW);   // 49968 for last
}
static __device__ __forceinline__ int scol(int idx) {
  return chunk_base(idx >> 5) + (idx & 31);
}

// ---------------- K1: sampled molid + W pack ----------------
__global__ __launch_bounds__(256) void k_prep(
    const float* __restrict__ mat, const float* __restrict__ W,
    int* __restrict__ smolid, int4* __restrict__ wp) {
  int b = blockIdx.x, t = threadIdx.x;
  if (b < NB_SAMP) {
    int base = chunk_base(b);
    int cp = (t & 15) * 2;      // column pair
    int rg = t >> 4;            // 16 row-groups of 32 rows
    int idx = -1, idy = -1;
    const float* p0 = mat + (size_t)(rg * 32) * N_NODES + base + cp;
#pragma unroll 16
    for (int r = 0; r < 32; r++) {
      float2 v = *(const float2*)(p0 + (size_t)r * N_NODES);
      if (v.x != 0.f) idx = rg * 32 + r;
      if (v.y != 0.f) idy = rg * 32 + r;
    }
    __shared__ int sm[16][32];
    sm[rg][cp] = idx; sm[rg][cp + 1] = idy;
    __syncthreads();
    if (t < 32) {
      int best = -1;
#pragma unroll
      for (int g = 0; g < 16; g++) best = max(best, sm[g][t]);
      smolid[b * CW + t] = best;
    }
  } else {
    // W pack into MFMA B-fragment layout (bf16)
    int g  = (b - NB_SAMP) * 256 + t;   // 0..8191
    int l  = g & 63;
    int Ju = g >> 6;
    int J  = Ju >> 3, u = Ju & 7;
    int j  = J * 16 + (l & 15);
    int k0 = u * 32 + (l >> 4) * 8;
    short sv[8];
#pragma unroll
    for (int i = 0; i < 8; i++) sv[i] = f2bf(W[(size_t)(k0 + i) * ODIM + j]);
    wp[Ju * 64 + l] = *(int4*)sv;
  }
}

// ---------------- K2: one block per molecule — bounds, align, softmax,
// full out1 row write, fused MFMA pool ----------------
__global__ __launch_bounds__(K2T, 2) void k_main(
    const float* __restrict__ x, const float* __restrict__ mat,
    const float* __restrict__ wa, const float* __restrict__ ba,
    const int* __restrict__ smolid, const int4* __restrict__ wp,
    const float* __restrict__ bias, float* __restrict__ out0,
    float* __restrict__ out1) {
  int m = blockIdx.x;
  int t = threadIdx.x;

  __shared__ float a_lds[A_CAP];
  __shared__ __align__(16) short xs[16 * 256];
  __shared__ float fred[8];
  __shared__ int   ired[8];
  __shared__ int   sseg[2];

  // ---- boundaries strt[m], strt[m+1] (uniform control flow per block)
  for (int which = 0; which < 2; which++) {
    int mm = m + which;
    int lo = 0, hi = NSAMP;
    while (lo < hi) { int mid = (lo + hi) >> 1; if (smolid[mid] < mm) lo = mid + 1; else hi = mid; }
    int res;
    if (lo == 0) res = 0;
    else if (lo >= NSAMP) res = N_NODES;
    else {
      int chi = scol(lo), clo = scol(lo - 1);
      if (chi == clo + 1) res = chi;
      else {
        // scan rows mm..bh over the gap (clo, chi]; first hit = boundary
        int bh = smolid[lo];
        res = -1;
        for (int r = mm; r <= bh; r++) {
          int f = 0x7fffffff;
          int col = clo + 1 + t;
          if (col <= chi && mat[(size_t)r * N_NODES + col] != 0.f) f = col;
#pragma unroll
          for (int o = 1; o < 64; o <<= 1) f = min(f, __shfl_xor(f, o));
          if ((t & 63) == 0) ired[t >> 6] = f;
          __syncthreads();
          int gmin = ired[0];
#pragma unroll
          for (int i = 1; i < 8; i++) gmin = min(gmin, ired[i]);
          __syncthreads();
          if (gmin != 0x7fffffff) { res = gmin; break; }
        }
        if (res < 0) res = chi;   // unreachable safety
      }
    }
    if (t == 0) sseg[which] = res;
  }
  __syncthreads();
  int seg_s = sseg[0], seg_e = sseg[1];
  int L = seg_e - seg_s;

  // ---- zero out1 row except the float4 window covering the segment
  int s4 = seg_s >> 2, e4 = (seg_e + 3) >> 2;
  float4* orow = (float4*)out1 + (size_t)m * NF4;
  float4 zz; zz.x = zz.y = zz.z = zz.w = 0.f;
  for (int q = t; q < NF4; q += K2T)
    if (q < s4 || q >= e4) orow[q] = zz;

  // ---- pass A: a[i] = x[seg_s+i,:].wa + ba   (8 threads per row)
  float ba0 = ba[0];
  int sub = t & 7;
  float4 wv[8];
  {
    const float4* wr = (const float4*)wa + sub * 8;
#pragma unroll
    for (int i = 0; i < 8; i++) wv[i] = wr[i];
  }
  int nit = (L + 63) >> 6;
  for (int it = 0; it < nit; it++) {
    int ro  = it * 64 + (t >> 3);
    int row = seg_s + ro;
    float s = 0.f;
    if (row < seg_e) {
      const float4* xr = (const float4*)(x + (size_t)row * DIMK) + sub * 8;
#pragma unroll
      for (int i = 0; i < 8; i++) {
        float4 xv = xr[i];
        s += xv.x * wv[i].x + xv.y * wv[i].y + xv.z * wv[i].z + xv.w * wv[i].w;
      }
    }
    s += __shfl_xor(s, 1); s += __shfl_xor(s, 2); s += __shfl_xor(s, 4);
    if (sub == 0 && row < seg_e && ro < A_CAP) a_lds[ro] = s + ba0;
  }
  __syncthreads();

  // ---- softmax stats over a_lds[0..L)
  float mx = -3e38f;
  for (int i = t; i < L; i += K2T) mx = fmaxf(mx, a_lds[i]);
#pragma unroll
  for (int o = 1; o < 64; o <<= 1) mx = fmaxf(mx, __shfl_xor(mx, o));
  if ((t & 63) == 0) fred[t >> 6] = mx;
  __syncthreads();
  mx = fred[0];
#pragma unroll
  for (int i = 1; i < 8; i++) mx = fmaxf(mx, fred[i]);
  __syncthreads();
  float sm = 0.f;
  for (int i = t; i < L; i += K2T) sm += __expf(a_lds[i] - mx);
#pragma unroll
  for (int o = 1; o < 64; o <<= 1) sm += __shfl_xor(sm, o);
  if ((t & 63) == 0) fred[t >> 6] = sm;
  __syncthreads();
  sm = 0.f;
#pragma unroll
  for (int i = 0; i < 8; i++) sm += fred[i];
  float inv = (sm > 0.f) ? 1.f / sm : 0.f;
  for (int i = t; i < L; i += K2T) a_lds[i] = __expf(a_lds[i] - mx) * inv;
  __syncthreads();

  // ---- segment window of out1 row (weights)
  for (int q = s4 + t; q < e4; q += K2T) {
    int n = q * 4;
    float4 o;
    o.x = (n     >= seg_s && n     < seg_e) ? a_lds[n     - seg_s] : 0.f;
    o.y = (n + 1 >= seg_s && n + 1 < seg_e) ? a_lds[n + 1 - seg_s] : 0.f;
    o.z = (n + 2 >= seg_s && n + 2 < seg_e) ? a_lds[n + 2 - seg_s] : 0.f;
    o.w = (n + 3 >= seg_s && n + 3 < seg_e) ? a_lds[n + 3 - seg_s] : 0.f;
    orow[q] = o;
  }

  // ---- fused h-GEMM + pool (x re-read is L2-hot: same rows as pass A)
  int wv_id = t >> 6, l = t & 63;
  bf16x8 wfrag[2][8];
#pragma unroll
  for (int t2 = 0; t2 < 2; t2++)
#pragma unroll
    for (int u = 0; u < 8; u++)
      wfrag[t2][u] = __builtin_bit_cast(bf16x8, wp[((wv_id * 2 + t2) * 8 + u) * 64 + l]);
  float bias_r[2];
#pragma unroll
  for (int t2 = 0; t2 < 2; t2++) bias_r[t2] = bias[wv_id * 32 + t2 * 16 + (l & 15)];

  float pooled[2] = {0.f, 0.f};
  int r = l & 15, g = l >> 4;
  int swr = (r & 7) << 4;

  int srow = t >> 5;            // staging: 16 rows, 32 threads each
  int c0b  = (t & 31) * 16;     // byte col offset within row
  int ssw  = (srow & 7) << 4;
  char* lb = (char*)xs;

  int nt2 = (L + 15) >> 4;
  for (int tile = 0; tile < nt2; tile++) {
    int base = seg_s + tile * 16;
    __syncthreads();
    {
      int n = base + srow;
      short sv[8];
      if (n < seg_e) {
        const float4* src = (const float4*)(x + (size_t)n * DIMK) + (t & 31) * 2;
        float4 A = src[0], B = src[1];
        sv[0] = f2bf(A.x); sv[1] = f2bf(A.y); sv[2] = f2bf(A.z); sv[3] = f2bf(A.w);
        sv[4] = f2bf(B.x); sv[5] = f2bf(B.y); sv[6] = f2bf(B.z); sv[7] = f2bf(B.w);
      } else {
#pragma unroll
        for (int i = 0; i < 8; i++) sv[i] = 0;
      }
      *(int4*)(lb + (srow << 9) + (c0b ^ ssw)) = *(int4*)sv;
    }
    __syncthreads();
    bf16x8 af[8];
#pragma unroll
    for (int u = 0; u < 8; u++)
      af[u] = __builtin_bit_cast(bf16x8,
                *(const int4*)(lb + (r << 9) + (((u << 6) + (g << 4)) ^ swr)));
#pragma unroll
    for (int t2 = 0; t2 < 2; t2++) {
      f32x4 acc = {0.f, 0.f, 0.f, 0.f};
#pragma unroll
      for (int u = 0; u < 8; u++)
        acc = __builtin_amdgcn_mfma_f32_16x16x32_bf16(af[u], wfrag[t2][u], acc, 0, 0, 0);
      float p = 0.f;
#pragma unroll
      for (int i = 0; i < 4; i++) {
        int ridx = tile * 16 + (g << 2) + i;
        float wgt = (ridx < L) ? a_lds[ridx] : 0.f;
        float h = acc[i] + bias_r[t2];
        h = h > 0.f ? h : 0.01f * h;
        p += wgt * h;
      }
      pooled[t2] += p;
    }
  }
#pragma unroll
  for (int t2 = 0; t2 < 2; t2++) {
    float p = pooled[t2];
    p += __shfl_xor(p, 16);
    p += __shfl_xor(p, 32);
    pooled[t2] = p;
  }
  if (l < 16) {
#pragma unroll
    for (int t2 = 0; t2 < 2; t2++)
      out0[m * ODIM + wv_id * 32 + t2 * 16 + l] = pooled[t2];
  }
}

extern "C" void kernel_launch(void* const* d_in, const int* in_sizes, int n_in,
                              void* d_out, int out_size, void* d_ws, size_t ws_size,
                              hipStream_t stream) {
  const float* x   = (const float*)d_in[0];
  const float* mat = (const float*)d_in[1];
  // d_in[2] (mol_node_mask) redundant with mol_node_matrix — never read
  const float* W   = (const float*)d_in[3];
  const float* bA  = (const float*)d_in[4];
  const float* wa  = (const float*)d_in[5];
  const float* ba  = (const float*)d_in[6];

  float* out0 = (float*)d_out;
  float* out1 = out0 + (size_t)M_MOLS * ODIM;

  char* ws     = (char*)d_ws;
  int*  smolid = (int*) (ws);            // 3168 ints
  int4* wp     = (int4*)(ws + 16384);    // 128 KiB

  k_prep<<<K1_GRID, 256, 0, stream>>>(mat, W, smolid, wp);
  k_main<<<M_MOLS, K2T, 0, stream>>>(x, mat, wa, ba, smolid, wp, bA, out0, out1);
}